// Round 7
// baseline (577.982 us; speedup 1.0000x reference)
//
#include <hip/hip_runtime.h>
#include <cstdint>

typedef float f32x4 __attribute__((ext_vector_type(4)));

constexpr int N_TOK = 32768;
constexpr int DIM   = 1024;
constexpr int NEXP  = 64;
constexpr float CAPACITY = 40960.0f;   // int(1.25 * 32768)
constexpr float EPS_DEN  = 1e-6f;

// Persistent device scratch
__device__ float  g_sums[192];             // [0..63]=denom, [64..127]=imp, [128..191]=load
__device__ float4 g_rec[N_TOK];            // per-row: {raw1, raw2, idx1, idx2}
__device__ float  g_part[4][NEXP][N_TOK];  // K-quarter partial logits, [q][e][t] (32 MB)

__global__ void init_sums() {
    if (threadIdx.x < 192) g_sums[threadIdx.x] = 0.0f;
}

// ---------------------------------------------------------------------------
// gemm_part: one K-quarter (256 k) of logits for 512 tokens.
//   512 thr = 16 expert-cols x 32 row-slots; thread tile M'=16 tok x N'=4 exp.
//   W: LDS 16KB chunks (64 exp x 64 k), double-buffered, XOR-col swizzle
//      (slot = e*16 + (k4 ^ ((e>>2)&15)) -> 2-way conflicts only).
//   x: per-lane global b128, 16-lane broadcast-merged, k4-double-buffered.
//   grid = 64 token-groups x 4 K-quarters = 256 blocks (1/CU, 2 waves/SIMD).
// ---------------------------------------------------------------------------
#define MT 16
#define NT 4

__global__ __launch_bounds__(512, 2)
void gemm_part(const float* __restrict__ x, const float* __restrict__ wg) {
    __shared__ f32x4 wbuf[2][NEXP * 16];   // 32 KB

    const int tid  = threadIdx.x;
    const int cc   = tid & 15;             // expert col: experts 4*cc..4*cc+3
    const int rs   = tid >> 4;             // row slot 0..31
    const int kq   = blockIdx.x & 3;       // K-quarter
    const int tg   = blockIdx.x >> 2;      // token group 0..63
    const int tbase = tg * 512 + rs * MT;  // first token of this thread

    const float* xrow = x + (size_t)tbase * DIM + kq * 256;   // per-lane base
    const float* wq   = wg + kq * 256;

    float acc[MT][NT];
#pragma unroll
    for (int m = 0; m < MT; ++m)
#pragma unroll
        for (int n = 0; n < NT; ++n) acc[m][n] = 0.0f;

    f32x4 xa[MT], xb[MT], wst[2];

#define PF(X, kk) do { _Pragma("unroll")                                      \
    for (int m_ = 0; m_ < MT; ++m_)                                           \
        X[m_] = *(const f32x4*)(xrow + (size_t)m_ * DIM + (kk) * 4);          \
    } while (0)

#define COMP(X, kk) do {                                                      \
    const int k4s_ = (kk) & 15;                                               \
    const int bf_  = ((kk) >> 4) & 1;                                         \
    _Pragma("unroll")                                                         \
    for (int n_ = 0; n_ < NT; ++n_) {                                         \
        f32x4 w_ = wbuf[bf_][(4 * cc + n_) * 16 + (k4s_ ^ cc)];               \
        _Pragma("unroll")                                                     \
        for (int m_ = 0; m_ < MT; ++m_) {                                     \
            acc[m_][n_] = fmaf(X[m_].x, w_.x, acc[m_][n_]);                   \
            acc[m_][n_] = fmaf(X[m_].y, w_.y, acc[m_][n_]);                   \
            acc[m_][n_] = fmaf(X[m_].z, w_.z, acc[m_][n_]);                   \
            acc[m_][n_] = fmaf(X[m_].w, w_.w, acc[m_][n_]);                   \
        }                                                                     \
    } } while (0)

#define WLOAD(c) do { _Pragma("unroll")                                       \
    for (int i_ = 0; i_ < 2; ++i_) {                                          \
        int j_ = tid + 512 * i_, e_ = j_ >> 4, ks_ = j_ & 15;                 \
        wst[i_] = *(const f32x4*)(wq + (size_t)e_ * DIM + (c) * 64            \
                                   + ((ks_ ^ ((e_ >> 2) & 15)) << 2));        \
    } } while (0)

#define WCOMMIT(c) do { _Pragma("unroll")                                     \
    for (int i_ = 0; i_ < 2; ++i_)                                            \
        wbuf[(c) & 1][tid + 512 * i_] = wst[i_];                              \
    } while (0)

    // prologue: x(k4=0) in flight; stage W chunk 0; barrier
    PF(xa, 0);
    WLOAD(0);
    WCOMMIT(0);
    __syncthreads();

    for (int kp = 0; kp < 32; ++kp) {
        const int kk = kp * 2;
        const int c  = kk >> 4;
        if ((kk & 15) == 0 && c < 3) WLOAD(c + 1);   // issue next W chunk early
        PF(xb, kk + 1);
        COMP(xa, kk);
        if (kp < 31) PF(xa, kk + 2);
        COMP(xb, kk + 1);
        if ((kk & 15) == 14 && c < 3) {              // commit next chunk, 1 barrier
            WCOMMIT(c + 1);
            __syncthreads();
        }
    }

    // write partials: [q][e][t], 4 consecutive tokens per f32x4 store
#pragma unroll
    for (int n = 0; n < NT; ++n) {
        float* dst = &g_part[kq][4 * cc + n][tbase];
#pragma unroll
        for (int mg = 0; mg < 4; ++mg) {
            f32x4 v = {acc[mg * 4 + 0][n], acc[mg * 4 + 1][n],
                       acc[mg * 4 + 2][n], acc[mg * 4 + 3][n]};
            *(f32x4*)(dst + mg * 4) = v;
        }
    }
#undef PF
#undef COMP
#undef WLOAD
#undef WCOMMIT
}

// ---------------------------------------------------------------------------
// combine: per token sum 4 K-quarter partials + bias -> softmax -> top-2 ->
// per-expert sums (denom/importance/load) + per-token record.
//   thread = token; 128 thr/block, grid 256; reads fully coalesced ([q][e][t]).
// ---------------------------------------------------------------------------
__global__ __launch_bounds__(128)
void combine(const float* __restrict__ bg) {
    __shared__ float rawT[128 * 65];
    __shared__ float ws[192];

    const int tid = threadIdx.x;
    const int t   = blockIdx.x * 128 + tid;

    for (int i = tid; i < 192; i += 128) ws[i] = 0.0f;
    __syncthreads();

    float lg[NEXP];
#pragma unroll
    for (int e = 0; e < NEXP; ++e) {
        lg[e] = (g_part[0][e][t] + g_part[1][e][t])
              + (g_part[2][e][t] + g_part[3][e][t]) + bg[e];
    }

    // top-2, earliest index on ties (matches lax.top_k)
    float b1 = -INFINITY, b2 = -INFINITY; int i1 = 0, i2 = 0;
#pragma unroll
    for (int e = 0; e < NEXP; ++e) {
        float v = lg[e];
        if (v > b1)      { b2 = b1; i2 = i1; b1 = v; i1 = e; }
        else if (v > b2) { b2 = v;  i2 = e; }
    }

    float s = 0.0f;
#pragma unroll
    for (int e = 0; e < NEXP; ++e) {
        float ev = expf(lg[e] - b1);
        lg[e] = ev;
        s += ev;
    }
    const float inv  = 1.0f / s;
    const float raw1 = inv;                   // exp(b1-b1)*inv
    const float raw2 = expf(b2 - b1) * inv;

    // importance: transpose through padded LDS, 64 threads sum columns
#pragma unroll
    for (int e = 0; e < NEXP; ++e) rawT[tid * 65 + e] = lg[e] * inv;
    __syncthreads();
    if (tid < NEXP) {
        float imp = 0.0f;
#pragma unroll
        for (int tt = 0; tt < 128; ++tt) imp += rawT[tt * 65 + tid];
        atomicAdd(&g_sums[64 + tid], imp);
    }

    // denom / load via LDS, then one global atomic per expert per block
    atomicAdd(&ws[i1], raw1);
    atomicAdd(&ws[i2], raw2);
    atomicAdd(&ws[128 + i1], 1.0f);
    atomicAdd(&ws[128 + i2], 1.0f);
    g_rec[t] = make_float4(raw1, raw2, __int_as_float(i1), __int_as_float(i2));

    __syncthreads();
    if (tid < NEXP) {
        atomicAdd(&g_sums[tid],       ws[tid]);
        atomicAdd(&g_sums[128 + tid], ws[128 + tid]);
    }
}

// ---------------------------------------------------------------------------
// scatter: scale[e]=capacity/(denom+eps); block 0 emits aux loss.
// 16 threads/row, one float4 store each; 16 rows/block.
// ---------------------------------------------------------------------------
__global__ __launch_bounds__(256)
void scatter_out(float* __restrict__ out) {
    __shared__ float scale_s[NEXP];
    int tid = threadIdx.x;
    if (tid < NEXP) {
        float den = g_sums[tid];
        scale_s[tid] = CAPACITY / (den + EPS_DEN);
        if (blockIdx.x == 0) {
            float prod = g_sums[64 + tid] * g_sums[128 + tid];
#pragma unroll
            for (int off = 32; off; off >>= 1) prod += __shfl_xor(prod, off);
            if (tid == 0) {
                // aux = 0.01 * mean_e(impSum*loadSum / N^2) * 64^2
                out[(size_t)N_TOK * NEXP] =
                    0.64f * prod / ((float)N_TOK * (float)N_TOK);
            }
        }
    }
    __syncthreads();

    int row = blockIdx.x * 16 + (tid >> 4);
    int g   = tid & 15;

    float4 rec = g_rec[row];
    int i1 = __float_as_int(rec.z);
    int i2 = __float_as_int(rec.w);
    float s1 = rec.x * scale_s[i1];
    float s2 = rec.y * scale_s[i2];

    int base = g * 4;
    float4 o;
    o.x = (i1 == base + 0) ? s1 : ((i2 == base + 0) ? s2 : 0.0f);
    o.y = (i1 == base + 1) ? s1 : ((i2 == base + 1) ? s2 : 0.0f);
    o.z = (i1 == base + 2) ? s1 : ((i2 == base + 2) ? s2 : 0.0f);
    o.w = (i1 == base + 3) ? s1 : ((i2 == base + 3) ? s2 : 0.0f);

    ((float4*)out)[(size_t)row * 16 + g] = o;
}

// ---------------------------------------------------------------------------
extern "C" void kernel_launch(void* const* d_in, const int* in_sizes, int n_in,
                              void* d_out, int out_size, void* d_ws, size_t ws_size,
                              hipStream_t stream) {
    const float* x  = (const float*)d_in[0];
    const float* wg = (const float*)d_in[1];
    const float* bg = (const float*)d_in[2];
    float* out = (float*)d_out;

    hipLaunchKernelGGL(init_sums, dim3(1), dim3(256), 0, stream);
    hipLaunchKernelGGL(gemm_part, dim3(256), dim3(512), 0, stream, x, wg);
    hipLaunchKernelGGL(combine, dim3(N_TOK / 128), dim3(128), 0, stream, bg);
    hipLaunchKernelGGL(scatter_out, dim3(N_TOK / 16), dim3(256), 0, stream, out);
}